// Round 3
// baseline (256.464 us; speedup 1.0000x reference)
//
#include <hip/hip_runtime.h>

// SequentialEdge: B=256 graphs, R=256 residues/graph, A=8 atoms/residue, D=2.
// Output (int32): 5 chunks (i=-2..2), chunk i has B*(R-|i|)*A*A rows of
// [node_in, node_out, i+D]; rows are -1 where chain_id differs; trailing
// scalar (2D+1)=5 at int index 62,619,648.
//
// Mapping: one WAVE per 8 residue segments (chunk z, graph g, slots rv0..rv0+7).
// A segment = 64 edges = 192 ints = 48 int4, and every segment start is
// 16B-aligned. The wave's 8 segments form 384 consecutive int4; ALL 64 lanes
// store: 6 full-width (1024 B) contiguous dwordx4 stores per wave (previous
// rounds used 48/64 lanes = 768 B/instr). Per store u, lane l covers int4
// k = 64u + l, which lies in segment s = k/48 (only two candidates per u,
// resolved by one compare against a compile-time split lane -> the per-segment
// resin[]/same[] arrays are indexed with compile-time constants, no scratch).
//
// Chunk table (int4 units, 48 int4 per segment):
//   z=0 (i=-2): Rv=254 lo=2 base4=0
//   z=1 (i=-1): Rv=255 lo=1 base4=3,121,152
//   z=2 (i= 0): Rv=256 lo=0 base4=6,254,592
//   z=3 (i=+1): Rv=255 lo=0 base4=9,400,320
//   z=4 (i=+2): Rv=254 lo=0 base4=12,533,760   (total 15,654,912 int4)

#define INT_TOTAL 62619648u
#define NSEG 8          // segments per wave -> 6 full-width stores per lane

typedef int iv4 __attribute__((ext_vector_type(4)));

__global__ __launch_bounds__(256)
void seqedge_kernel(const int* __restrict__ chain, int* __restrict__ out) {
    const int z     = (int)blockIdx.z;     // relation id 0..4, offset i = z-2
    const int ioff  = z - 2;
    const int absio = ioff < 0 ? -ioff : ioff;
    const int Rv    = 256 - absio;
    const int lo    = ioff < 0 ? -ioff : 0;

    static const unsigned base4_tab[5] = {0u, 3121152u, 6254592u, 9400320u, 12533760u};
    const unsigned base4 = base4_tab[z];

    // trailing scalar: num_relation = 2D+1
    if (threadIdx.x == 0u && blockIdx.x == 0u && blockIdx.y == 0u && blockIdx.z == 0u)
        out[INT_TOTAL] = 5;

    const unsigned l  = threadIdx.x & 63u;
    const unsigned w  = threadIdx.x >> 6;                  // wave id in block
    const int      g  = (int)blockIdx.y;
    const int    rv0  = (int)((blockIdx.x * 4u + w) * NSEG);

    // Wave-uniform per-segment data (chain loads are L1/L2-broadcast).
    int  resin[NSEG];
    bool same[NSEG];
    #pragma unroll
    for (int s = 0; s < NSEG; ++s) {
        const int rv = rv0 + s;
        resin[s] = g * 256 + lo + rv;
        same[s]  = (rv < Rv) && (chain[resin[s]] == chain[resin[s] + ioff]);
    }

    // Wave's first int4 (lane-adjusted); store u goes to gb4 + 64*u.
    const unsigned gb4 = base4 + (unsigned)(g * Rv + rv0) * 48u + l;

    #pragma unroll
    for (unsigned u = 0; u < (48u * NSEG) / 64u; ++u) {    // 6 stores
        const unsigned a      = (64u * u) / 48u;           // low candidate segment (compile-time)
        const unsigned splitl = 48u * (a + 1u) - 64u * u;  // lane where segment increments (48/32/16)
        const bool     hiseg  = (l >= splitl);
        const unsigned s      = hiseg ? a + 1u : a;
        const int      rin    = hiseg ? resin[a + 1u] : resin[a];  // compile-time indices
        const bool     sm     = hiseg ? same[a + 1u]  : same[a];
        const unsigned p      = (64u * u + l) - 48u * s;   // int4 position within segment, <48

        iv4 v;
        if (!sm) {
            v = (iv4){-1, -1, -1, -1};
        } else {
            // position p covers ints j0..j0+3 of the segment (j = edge*3 + comp)
            const unsigned j0 = p * 4u;
            const unsigned e0 = j0 / 3u;                   // magic mul, e0 <= 62
            const unsigned c0 = j0 - e0 * 3u;
            const unsigned e1 = e0 + 1u;                   // <= 63: stays in-segment
            const int ri8 = rin * 8, ro8 = (rin + ioff) * 8;
            const int x0 = ri8 + (int)(e0 >> 3), y0 = ro8 + (int)(e0 & 7u);
            const int x1 = ri8 + (int)(e1 >> 3), y1 = ro8 + (int)(e1 & 7u);
            if (c0 == 0u)      v = (iv4){x0, y0, z,  x1};
            else if (c0 == 1u) v = (iv4){y0, z,  x1, y1};
            else               v = (iv4){z,  x1, y1, z };
        }
        // Tail guard: short chunks (Rv<256) have no slots for rv>=Rv; writing
        // them would clobber the next graph's block. Per-lane predicated.
        if (rv0 + (int)s < Rv)
            reinterpret_cast<iv4*>(out)[gb4 + 64u * u] = v;
    }
}

extern "C" void kernel_launch(void* const* d_in, const int* in_sizes, int n_in,
                              void* d_out, int out_size, void* d_ws, size_t ws_size,
                              hipStream_t stream) {
    const int* chain_id = (const int*)d_in[0];
    int* out = (int*)d_out;
    // x: 8 blocks x 4 waves x NSEG=8 segments = 256 residue slots (covers Rv<=256)
    // y: graph, z: chunk
    dim3 grid(8, 256, 5);
    seqedge_kernel<<<grid, 256, 0, stream>>>(chain_id, out);
}